// Round 3
// baseline (97.897 us; speedup 1.0000x reference)
//
#include <hip/hip_runtime.h>
#include <hip/hip_bf16.h>
#include <math.h>

#define NPATH 6
#define NINST 20000
#define PLEN 4
#define DFEAT 128
#define TPB1 512
#define WPB1 (TPB1 / 64)      // 8 waves per block
#define BPP 128               // blocks per path
#define WPP (BPP * WPB1)      // 1024 waves per path

// ---------------------------------------------------------------------------
// Pass 1 (fused): per block, compute u1[m]=W_enc[m]@Wa1, u2[m]=W_enc[m]@Wa2,
// c[m]=b_enc[m]·(Wa1+Wa2)+b_att[e] in LDS (W_enc is L2-resident after first
// touch), then run the online-softmax gather:
//   s = g0·u1 + g3·u2 + c ; leaky_relu ; online max/sum/V update.
// Software pipeline: indices 2 iters ahead (int4 = both node ids in one load),
// feature rows 1 iter ahead. First gather issued BEFORE u-compute.
// grid = NPATH*BPP × TPB1
// ---------------------------------------------------------------------------
__global__ __launch_bounds__(TPB1) void k_pass1(
    const float* __restrict__ feat, const int* __restrict__ inst,
    const float* __restrict__ W_enc, const float* __restrict__ b_enc,
    const float* __restrict__ W_att, const float* __restrict__ b_att,
    const int* __restrict__ etype,
    float* __restrict__ pV, float* __restrict__ pM, float* __restrict__ pS)
{
    int m   = blockIdx.x / BPP;
    int bw  = blockIdx.x % BPP;
    int tid = threadIdx.x;
    int wv  = tid >> 6, lane = tid & 63;
    int w   = bw * WPB1 + wv;               // wave within path [0, WPP)

    __shared__ float swa[2 * DFEAT];
    __shared__ float su1[DFEAT], su2[DFEAT];
    __shared__ float sbc[DFEAT];
    __shared__ float scv;

    // ---- issue first gather early (addresses independent of u) ----
    const int4* ib4 = (const int4*)(inst + (size_t)m * NINST * PLEN);
    int i = w;
    int4 ia = ib4[i];                        // {pos0, pos1, pos2, pos3} of instance i
    float2 f0 = ((const float2*)(feat + (size_t)ia.x * DFEAT))[lane];
    float2 f3 = ((const float2*)(feat + (size_t)ia.w * DFEAT))[lane];
    int inx = i + WPP;
    int4 ib = ia;
    if (inx < NINST) ib = ib4[inx];

    // ---- u1/u2/cvec in LDS (overlaps with the loads above) ----
    int e = etype[m];
    {
        const float* wa = W_att + (size_t)e * (2 * DFEAT);
        if (tid < 2 * DFEAT) swa[tid] = wa[tid];
    }
    __syncthreads();
    if (tid < DFEAT) {
        const float4* Wr = (const float4*)(W_enc + ((size_t)m * DFEAT + tid) * DFEAT);
        float s1 = 0.f, s2 = 0.f;
        #pragma unroll 8
        for (int q = 0; q < DFEAT / 4; ++q) {
            float4 w4 = Wr[q];
            s1 += w4.x * swa[4*q]       + w4.y * swa[4*q+1]
                + w4.z * swa[4*q+2]     + w4.w * swa[4*q+3];
            s2 += w4.x * swa[DFEAT+4*q]   + w4.y * swa[DFEAT+4*q+1]
                + w4.z * swa[DFEAT+4*q+2] + w4.w * swa[DFEAT+4*q+3];
        }
        su1[tid] = s1;
        su2[tid] = s2;
        sbc[tid] = b_enc[m * DFEAT + tid] * (swa[tid] + swa[DFEAT + tid]);
    }
    __syncthreads();
    if (tid < 64) {
        float t = sbc[tid] + sbc[tid + 64];
        #pragma unroll
        for (int o = 32; o; o >>= 1) t += __shfl_xor(t, o);
        if (tid == 0) scv = t + b_att[e];
    }
    __syncthreads();

    float2 U1 = ((const float2*)su1)[lane];
    float2 U2 = ((const float2*)su2)[lane];
    float c   = scv;

    // ---- online-softmax gather loop ----
    float mx = -3e38f, sum = 0.f, v0 = 0.f, v1 = 0.f;
    while (i < NINST) {
        int ipf = i + 2 * WPP;               // prefetch indices 2 ahead
        int4 ic = ib;
        if (ipf < NINST) ic = ib4[ipf];
        float2 g0 = f0, g3 = f3;             // prefetch rows 1 ahead (idx already resident)
        if (inx < NINST) {
            g0 = ((const float2*)(feat + (size_t)ib.x * DFEAT))[lane];
            g3 = ((const float2*)(feat + (size_t)ib.w * DFEAT))[lane];
        }

        float p = f0.x * U1.x + f0.y * U1.y + f3.x * U2.x + f3.y * U2.y;
        #pragma unroll
        for (int o = 32; o; o >>= 1) p += __shfl_xor(p, o);
        float s = p + c;
        s = s > 0.f ? s : 0.2f * s;          // leaky_relu(0.2)
        float ns    = fmaxf(mx, s);
        float scale = __expf(mx - ns);
        float pe    = __expf(s - ns);
        sum = sum * scale + pe;
        v0  = v0  * scale + pe * f3.x;
        v1  = v1  * scale + pe * f3.y;
        mx  = ns;

        f0 = g0; f3 = g3; ib = ic;
        i = inx; inx += WPP;
    }

    int p = m * WPP + w;
    ((float2*)(pV + (size_t)p * DFEAT))[lane] = make_float2(v0, v1);
    if (lane == 0) { pM[p] = mx; pS[p] = sum; }
}

// ---------------------------------------------------------------------------
// Pass 2: per path — combine WPP partials (flash-style), normalize, GEMV with
// W_enc, produce mp_out[m][:] and ms[m].  grid = 6 × 1024
// ---------------------------------------------------------------------------
__global__ __launch_bounds__(1024) void k_pass2(
    const float* __restrict__ pV, const float* __restrict__ pM, const float* __restrict__ pS,
    const float* __restrict__ W_enc, const float* __restrict__ b_enc,
    const float* __restrict__ w_mp, const float* __restrict__ b_mp,
    float* __restrict__ mp_out, float* __restrict__ ms)
{
    int m = blockIdx.x, tid = threadIdx.x;
    int lane = tid & 63, wvi = tid >> 6;     // 16 waves

    __shared__ float e[WPP];
    __shared__ float red[16];
    __shared__ float sS, sMx;
    __shared__ float sv[8][DFEAT];
    __shared__ float sVn[DFEAT];
    __shared__ float smp[DFEAT];

    // 1) global max over WPP wave maxima
    float mv = pM[m * WPP + tid];
    float mx = mv;
    #pragma unroll
    for (int o = 32; o; o >>= 1) mx = fmaxf(mx, __shfl_xor(mx, o));
    if (lane == 0) red[wvi] = mx;
    __syncthreads();
    if (tid == 0) {
        float t = red[0];
        #pragma unroll
        for (int k = 1; k < 16; ++k) t = fmaxf(t, red[k]);
        sMx = t;
    }
    __syncthreads();
    float M = sMx;

    // 2) e_w = exp(m_w - M);  S = sum_w e_w * s_w
    float ew = __expf(mv - M);
    e[tid] = ew;
    float ssum = ew * pS[m * WPP + tid];
    #pragma unroll
    for (int o = 32; o; o >>= 1) ssum += __shfl_xor(ssum, o);
    if (lane == 0) red[wvi] = ssum;
    __syncthreads();
    if (tid == 0) {
        float t = 0.f;
        #pragma unroll
        for (int k = 0; k < 16; ++k) t += red[k];
        sS = t;
    }
    __syncthreads();
    float Sinv = 1.f / sS;

    // 3) V[d] = sum_w e_w * pV[w][d]
    int d = tid & 127, slice = tid >> 7;     // 8 slices of 128 dims
    float acc = 0.f;
    for (int wI = slice; wI < WPP; wI += 8)
        acc += e[wI] * pV[((size_t)(m * WPP + wI)) * DFEAT + d];
    sv[slice][d] = acc;
    __syncthreads();
    if (tid < DFEAT) {
        float t = 0.f;
        #pragma unroll
        for (int k = 0; k < 8; ++k) t += sv[k][tid];
        sVn[tid] = t * Sinv;
    }
    __syncthreads();

    // 4) GEMV: mp[h] = sVn · W[:,h] + b_enc[m][h]
    const float* W = W_enc + (size_t)m * DFEAT * DFEAT;
    float g = 0.f;
    for (int dd = slice; dd < DFEAT; dd += 8)
        g += sVn[dd] * W[(size_t)dd * DFEAT + d];
    __syncthreads();
    sv[slice][d] = g;
    __syncthreads();
    if (tid < DFEAT) {
        float t = b_enc[m * DFEAT + tid];
        #pragma unroll
        for (int k = 0; k < 8; ++k) t += sv[k][tid];
        mp_out[m * DFEAT + tid] = t;
        smp[tid] = t * w_mp[tid];
    }
    __syncthreads();

    // 5) ms[m] = mp · w_mp + b_mp
    if (tid < 64) {
        float t = smp[tid] + smp[tid + 64];
        #pragma unroll
        for (int o = 32; o; o >>= 1) t += __shfl_xor(t, o);
        if (tid == 0) ms[m] = t + b_mp[0];
    }
}

// ---------------------------------------------------------------------------
// Pass 3: cross-path softmax(leaky_relu(ms)) + blend + ELU.  1 block × 128.
// ---------------------------------------------------------------------------
__global__ void k_final(const float* __restrict__ mp_out, const float* __restrict__ ms,
                        float* __restrict__ out) {
    int h = threadIdx.x;
    float l[NPATH], mx = -3e38f;
    #pragma unroll
    for (int m = 0; m < NPATH; ++m) {
        float x = ms[m];
        x = x > 0.f ? x : 0.2f * x;
        l[m] = x;
        mx = fmaxf(mx, x);
    }
    float sum = 0.f;
    #pragma unroll
    for (int m = 0; m < NPATH; ++m) { l[m] = __expf(l[m] - mx); sum += l[m]; }
    float o = 0.f;
    #pragma unroll
    for (int m = 0; m < NPATH; ++m) o += (l[m] / sum) * mp_out[m * DFEAT + h];
    out[h] = o > 0.f ? o : __expf(o) - 1.f;   // elu
}

// ---------------------------------------------------------------------------
extern "C" void kernel_launch(void* const* d_in, const int* in_sizes, int n_in,
                              void* d_out, int out_size, void* d_ws, size_t ws_size,
                              hipStream_t stream) {
    const float* features   = (const float*)d_in[0];
    const float* W_enc      = (const float*)d_in[1];
    const float* b_enc      = (const float*)d_in[2];
    const float* W_att      = (const float*)d_in[3];
    const float* b_att      = (const float*)d_in[4];
    const float* w_mp       = (const float*)d_in[5];
    const float* b_mp       = (const float*)d_in[6];
    const int*   instances  = (const int*)d_in[7];
    const int*   edge_types = (const int*)d_in[8];
    float* out = (float*)d_out;
    float* ws  = (float*)d_ws;

    // workspace layout (floats)
    float* pV     = ws;                                   // NPATH*WPP*128 = 786432
    float* pM     = pV + (size_t)NPATH * WPP * DFEAT;     // 6144
    float* pS     = pM + NPATH * WPP;                     // 6144
    float* mp_out = pS + NPATH * WPP;                     // 768
    float* msv    = mp_out + NPATH * DFEAT;               // 6

    k_pass1<<<NPATH * BPP, TPB1, 0, stream>>>(features, instances, W_enc, b_enc,
                                              W_att, b_att, edge_types, pV, pM, pS);

    k_pass2<<<NPATH, 1024, 0, stream>>>(pV, pM, pS, W_enc, b_enc, w_mp, b_mp, mp_out, msv);

    k_final<<<1, DFEAT, 0, stream>>>(mp_out, msv, out);
}

// Round 4
// 65.944 us; speedup vs baseline: 1.4846x; 1.4846x over previous
//
#include <hip/hip_runtime.h>
#include <hip/hip_bf16.h>
#include <math.h>

#define NPATH 6
#define NINST 20000
#define PLEN 4
#define DFEAT 128
#define TPB1 256            // threads per pass1 block
#define WPB 4               // waves per block
#define GPW 4               // instance-groups per wave (16 lanes each)
#define GPB (WPB * GPW)     // 16 groups per block
#define BPP 128             // blocks per path
#define GPP (BPP * GPB)     // 2048 groups (instance streams) per path

__device__ __forceinline__ float dot4(float4 a, float4 b) {
    return a.x * b.x + a.y * b.y + a.z * b.z + a.w * b.w;
}

// ---------------------------------------------------------------------------
// Pass 1: fused u-precompute + online-softmax gather.
// Each 16-lane group owns one instance stream; lane sub holds dims
// [sub*4, sub*4+4) and [64+sub*4, 64+sub*4+4) of every row (2x float4).
// Per wave-iteration: 4 instances, 8 coalesced dwordx4 row loads (4KB),
// 4 shfl_xor (reduce within 16 lanes), 2 expf.
// Block epilogue: flash-combine the 16 group states in LDS -> one partial
// (V[128], m, s) per block.
// grid = NPATH*BPP x TPB1
// ---------------------------------------------------------------------------
__global__ __launch_bounds__(TPB1, 4) void k_pass1(
    const float* __restrict__ feat, const int* __restrict__ inst,
    const float* __restrict__ W_enc, const float* __restrict__ b_enc,
    const float* __restrict__ W_att, const float* __restrict__ b_att,
    const int* __restrict__ etype,
    float* __restrict__ pV, float* __restrict__ pM, float* __restrict__ pS)
{
    int m    = blockIdx.x / BPP;
    int bw   = blockIdx.x % BPP;
    int tid  = threadIdx.x;
    int wv   = tid >> 6, lane = tid & 63;
    int grp  = lane >> 4, sub = lane & 15;
    int gid  = wv * GPW + grp;              // group within block [0,16)
    int g    = bw * GPB + gid;              // group within path  [0,2048)

    __shared__ float swa[2 * DFEAT];
    __shared__ float su1[DFEAT], su2[DFEAT];
    __shared__ float sbc[DFEAT];
    __shared__ float scv;
    __shared__ float sV[GPB][DFEAT + 4];    // +4 pad: kill bank conflicts
    __shared__ float sMx[GPB], sSm[GPB];

    // ---- issue first gather immediately (independent of u) ----
    const int4* ib4 = (const int4*)(inst + (size_t)m * NINST * PLEN);
    int i = g;
    int4 ja = ib4[i];
    const float4* r0 = (const float4*)(feat + (size_t)ja.x * DFEAT);
    const float4* r3 = (const float4*)(feat + (size_t)ja.w * DFEAT);
    float4 f0a = r0[sub], f0b = r0[sub + 16];
    float4 f3a = r3[sub], f3b = r3[sub + 16];
    int4 jb = ib4[i + GPP];                 // i+GPP = g+2048 < 20000 always

    // ---- u1/u2/c in LDS (overlaps the loads above) ----
    int e = etype[m];
    swa[tid] = W_att[(size_t)e * (2 * DFEAT) + tid];   // TPB1 == 2*DFEAT
    __syncthreads();
    if (tid < DFEAT) {
        const float4* Wr = (const float4*)(W_enc + ((size_t)m * DFEAT + tid) * DFEAT);
        float s1 = 0.f, s2 = 0.f;
        #pragma unroll 8
        for (int q = 0; q < DFEAT / 4; ++q) {
            float4 w4 = Wr[q];
            s1 += w4.x * swa[4*q]         + w4.y * swa[4*q+1]
                + w4.z * swa[4*q+2]       + w4.w * swa[4*q+3];
            s2 += w4.x * swa[DFEAT+4*q]   + w4.y * swa[DFEAT+4*q+1]
                + w4.z * swa[DFEAT+4*q+2] + w4.w * swa[DFEAT+4*q+3];
        }
        su1[tid] = s1;
        su2[tid] = s2;
        sbc[tid] = b_enc[m * DFEAT + tid] * (swa[tid] + swa[DFEAT + tid]);
    }
    __syncthreads();
    if (tid < 64) {
        float t = sbc[tid] + sbc[tid + 64];
        #pragma unroll
        for (int o = 32; o; o >>= 1) t += __shfl_xor(t, o);
        if (tid == 0) scv = t + b_att[e];
    }
    __syncthreads();

    float4 U1a = ((const float4*)su1)[sub], U1b = ((const float4*)su1)[sub + 16];
    float4 U2a = ((const float4*)su2)[sub], U2b = ((const float4*)su2)[sub + 16];
    float c = scv;

    // ---- online-softmax gather loop (4 instances per wave-iter) ----
    float mx = -3e38f, sum = 0.f;
    float4 va = make_float4(0.f, 0.f, 0.f, 0.f);
    float4 vb = make_float4(0.f, 0.f, 0.f, 0.f);

    while (i < NINST) {
        int inx = i + GPP, ipf = i + 2 * GPP;
        int4 jc = jb;
        if (ipf < NINST) jc = ib4[ipf];
        float4 g0a = f0a, g0b = f0b, g3a = f3a, g3b = f3b;
        if (inx < NINST) {
            const float4* q0 = (const float4*)(feat + (size_t)jb.x * DFEAT);
            const float4* q3 = (const float4*)(feat + (size_t)jb.w * DFEAT);
            g0a = q0[sub]; g0b = q0[sub + 16];
            g3a = q3[sub]; g3b = q3[sub + 16];
        }

        float p = dot4(f0a, U1a) + dot4(f0b, U1b) + dot4(f3a, U2a) + dot4(f3b, U2b);
        p += __shfl_xor(p, 1);
        p += __shfl_xor(p, 2);
        p += __shfl_xor(p, 4);
        p += __shfl_xor(p, 8);              // all 16 lanes of group hold s
        float s = p + c;
        s = s > 0.f ? s : 0.2f * s;         // leaky_relu(0.2)
        float ns    = fmaxf(mx, s);
        float scale = __expf(mx - ns);
        float pe    = __expf(s - ns);
        sum = sum * scale + pe;
        va.x = va.x * scale + pe * f3a.x;  va.y = va.y * scale + pe * f3a.y;
        va.z = va.z * scale + pe * f3a.z;  va.w = va.w * scale + pe * f3a.w;
        vb.x = vb.x * scale + pe * f3b.x;  vb.y = vb.y * scale + pe * f3b.y;
        vb.z = vb.z * scale + pe * f3b.z;  vb.w = vb.w * scale + pe * f3b.w;
        mx = ns;

        f0a = g0a; f0b = g0b; f3a = g3a; f3b = g3b;
        jb = jc;
        i = inx;
    }

    // ---- block-level flash combine of 16 group states ----
    *(float4*)&sV[gid][sub * 4]      = va;
    *(float4*)&sV[gid][64 + sub * 4] = vb;
    if (sub == 0) { sMx[gid] = mx; sSm[gid] = sum; }
    __syncthreads();

    if (tid < DFEAT) {
        float M = sMx[0];
        #pragma unroll
        for (int k = 1; k < GPB; ++k) M = fmaxf(M, sMx[k]);
        float S = 0.f, V = 0.f;
        #pragma unroll
        for (int k = 0; k < GPB; ++k) {
            float ek = __expf(sMx[k] - M);
            S += ek * sSm[k];
            V += ek * sV[k][tid];
        }
        pV[(size_t)blockIdx.x * DFEAT + tid] = V;
        if (tid == 0) { pM[blockIdx.x] = M; pS[blockIdx.x] = S; }
    }
}

// ---------------------------------------------------------------------------
// Pass 2: per path — flash-combine 128 block partials, normalize, GEMV with
// W_enc, produce mp_out[m][:] and ms[m].  grid = 6 x 256
// ---------------------------------------------------------------------------
__global__ __launch_bounds__(256) void k_pass2(
    const float* __restrict__ pV, const float* __restrict__ pM, const float* __restrict__ pS,
    const float* __restrict__ W_enc, const float* __restrict__ b_enc,
    const float* __restrict__ w_mp, const float* __restrict__ b_mp,
    float* __restrict__ mp_out, float* __restrict__ ms)
{
    int m = blockIdx.x, tid = threadIdx.x;
    int d = tid & 127, slice = tid >> 7;    // 2 slices

    __shared__ float tmp[BPP];
    __shared__ float eL[BPP];
    __shared__ float sv[2][DFEAT];
    __shared__ float sVn[DFEAT];
    __shared__ float smp[DFEAT];
    __shared__ float sS, sMx;

    // 1) M = max over 128 block maxima
    if (tid < BPP) tmp[tid] = pM[m * BPP + tid];
    __syncthreads();
    for (int off = 64; off; off >>= 1) {
        if (tid < off) tmp[tid] = fmaxf(tmp[tid], tmp[tid + off]);
        __syncthreads();
    }
    if (tid == 0) sMx = tmp[0];
    __syncthreads();
    float M = sMx;

    // 2) e_k, S
    if (tid < BPP) {
        float ek = __expf(pM[m * BPP + tid] - M);
        eL[tid] = ek;
        tmp[tid] = ek * pS[m * BPP + tid];
    }
    __syncthreads();
    for (int off = 64; off; off >>= 1) {
        if (tid < off) tmp[tid] += tmp[tid + off];
        __syncthreads();
    }
    if (tid == 0) sS = tmp[0];
    __syncthreads();
    float Sinv = 1.f / sS;

    // 3) V[d] = sum_k e_k * pV[k][d]
    float acc = 0.f;
    for (int k = slice; k < BPP; k += 2)
        acc += eL[k] * pV[((size_t)(m * BPP + k)) * DFEAT + d];
    sv[slice][d] = acc;
    __syncthreads();
    if (tid < DFEAT) sVn[tid] = (sv[0][tid] + sv[1][tid]) * Sinv;
    __syncthreads();

    // 4) GEMV: mp[h] = sVn . W[:,h] + b_enc[m][h]
    const float* W = W_enc + (size_t)m * DFEAT * DFEAT;
    float gacc = 0.f;
    for (int dd = slice; dd < DFEAT; dd += 2)
        gacc += sVn[dd] * W[(size_t)dd * DFEAT + d];
    __syncthreads();
    sv[slice][d] = gacc;
    __syncthreads();
    if (tid < DFEAT) {
        float t = sv[0][tid] + sv[1][tid] + b_enc[m * DFEAT + tid];
        mp_out[m * DFEAT + tid] = t;
        smp[tid] = t * w_mp[tid];
    }
    __syncthreads();

    // 5) ms[m] = mp . w_mp + b_mp
    if (tid < 64) {
        float t = smp[tid] + smp[tid + 64];
        #pragma unroll
        for (int o = 32; o; o >>= 1) t += __shfl_xor(t, o);
        if (tid == 0) ms[m] = t + b_mp[0];
    }
}

// ---------------------------------------------------------------------------
// Pass 3: cross-path softmax(leaky_relu(ms)) + blend + ELU.  1 block x 128.
// ---------------------------------------------------------------------------
__global__ void k_final(const float* __restrict__ mp_out, const float* __restrict__ ms,
                        float* __restrict__ out) {
    int h = threadIdx.x;
    float l[NPATH], mx = -3e38f;
    #pragma unroll
    for (int m = 0; m < NPATH; ++m) {
        float x = ms[m];
        x = x > 0.f ? x : 0.2f * x;
        l[m] = x;
        mx = fmaxf(mx, x);
    }
    float sum = 0.f;
    #pragma unroll
    for (int m = 0; m < NPATH; ++m) { l[m] = __expf(l[m] - mx); sum += l[m]; }
    float o = 0.f;
    #pragma unroll
    for (int m = 0; m < NPATH; ++m) o += (l[m] / sum) * mp_out[m * DFEAT + h];
    out[h] = o > 0.f ? o : __expf(o) - 1.f;   // elu
}

// ---------------------------------------------------------------------------
extern "C" void kernel_launch(void* const* d_in, const int* in_sizes, int n_in,
                              void* d_out, int out_size, void* d_ws, size_t ws_size,
                              hipStream_t stream) {
    const float* features   = (const float*)d_in[0];
    const float* W_enc      = (const float*)d_in[1];
    const float* b_enc      = (const float*)d_in[2];
    const float* W_att      = (const float*)d_in[3];
    const float* b_att      = (const float*)d_in[4];
    const float* w_mp       = (const float*)d_in[5];
    const float* b_mp       = (const float*)d_in[6];
    const int*   instances  = (const int*)d_in[7];
    const int*   edge_types = (const int*)d_in[8];
    float* out = (float*)d_out;
    float* ws  = (float*)d_ws;

    const int nblk1 = NPATH * BPP;                    // 768

    // workspace layout (floats)
    float* pV     = ws;                               // 768*128 = 98304
    float* pM     = pV + (size_t)nblk1 * DFEAT;       // 768
    float* pS     = pM + nblk1;                       // 768
    float* mp_out = pS + nblk1;                       // 768
    float* msv    = mp_out + NPATH * DFEAT;           // 6

    k_pass1<<<nblk1, TPB1, 0, stream>>>(features, instances, W_enc, b_enc,
                                        W_att, b_att, edge_types, pV, pM, pS);

    k_pass2<<<NPATH, 256, 0, stream>>>(pV, pM, pS, W_enc, b_enc, w_mp, b_mp, mp_out, msv);

    k_final<<<1, DFEAT, 0, stream>>>(mp_out, msv, out);
}

// Round 5
// 65.529 us; speedup vs baseline: 1.4939x; 1.0063x over previous
//
#include <hip/hip_runtime.h>
#include <hip/hip_bf16.h>
#include <math.h>

#define NPATH 6
#define NINST 20000
#define PLEN 4
#define DFEAT 128
#define TPB1 256            // threads per pass1 block
#define WPB 4               // waves per block
#define GPW 4               // instance-groups per wave (16 lanes each)
#define GPB (WPB * GPW)     // 16 groups per block
#define BPP 128             // blocks per path
#define GPP (BPP * GPB)     // 2048 instance streams per path
#define RESCALE_THR 8.0f

__device__ __forceinline__ float dot4(float4 a, float4 b) {
    return a.x * b.x + a.y * b.y + a.z * b.z + a.w * b.w;
}

// ---------------------------------------------------------------------------
// Pass 1: fused u-precompute + online-softmax gather, 2-deep software pipeline.
// 16-lane group owns one instance stream; lane sub holds dims [sub*4,+4) and
// [64+sub*4,+4). Main loop is guard-free (precise vmcnt, 8KB in flight/wave);
// 2-step epilogue consumes the last prefetched register sets.
// Defer-max online softmax: rescale only when tmax exceeds m_ref + 8.
// grid = NPATH*BPP x TPB1
// ---------------------------------------------------------------------------
__global__ __launch_bounds__(TPB1, 4) void k_pass1(
    const float* __restrict__ feat, const int* __restrict__ inst,
    const float* __restrict__ W_enc, const float* __restrict__ b_enc,
    const float* __restrict__ W_att, const float* __restrict__ b_att,
    const int* __restrict__ etype,
    float* __restrict__ pV, float* __restrict__ pM, float* __restrict__ pS)
{
    int m    = blockIdx.x / BPP;
    int bw   = blockIdx.x % BPP;
    int tid  = threadIdx.x;
    int wv   = tid >> 6, lane = tid & 63;
    int grp  = lane >> 4, sub = lane & 15;
    int gid  = wv * GPW + grp;              // group within block [0,16)
    int g    = bw * GPB + gid;              // stream id within path [0,2048)

    __shared__ float swa[2 * DFEAT];
    __shared__ float su1[DFEAT], su2[DFEAT];
    __shared__ float sbc[DFEAT];
    __shared__ float scv;
    __shared__ float sV[GPB][DFEAT + 4];
    __shared__ float sMx[GPB], sSm[GPB];

    // ---- prologue: issue idx + two row-sets immediately ----
    const int4* ib4 = (const int4*)(inst + (size_t)m * NINST * PLEN);
    int i = g;
    int4 j0 = ib4[i];
    int4 j1 = ib4[i + GPP];
    int4 j2 = ib4[i + 2 * GPP];             // g+4096 < 20000 always

    const float4* r0 = (const float4*)(feat + (size_t)j0.x * DFEAT);
    const float4* r3 = (const float4*)(feat + (size_t)j0.w * DFEAT);
    float4 A0a = r0[sub], A0b = r0[sub + 16];
    float4 A3a = r3[sub], A3b = r3[sub + 16];
    const float4* q0 = (const float4*)(feat + (size_t)j1.x * DFEAT);
    const float4* q3 = (const float4*)(feat + (size_t)j1.w * DFEAT);
    float4 B0a = q0[sub], B0b = q0[sub + 16];
    float4 B3a = q3[sub], B3b = q3[sub + 16];

    // ---- u1/u2/c in LDS (overlaps the in-flight gathers) ----
    int e = etype[m];
    swa[tid] = W_att[(size_t)e * (2 * DFEAT) + tid];    // TPB1 == 2*DFEAT
    __syncthreads();
    if (tid < DFEAT) {
        const float4* Wr = (const float4*)(W_enc + ((size_t)m * DFEAT + tid) * DFEAT);
        float s1 = 0.f, s2 = 0.f;
        #pragma unroll 8
        for (int q = 0; q < DFEAT / 4; ++q) {
            float4 w4 = Wr[q];
            s1 += w4.x * swa[4*q]         + w4.y * swa[4*q+1]
                + w4.z * swa[4*q+2]       + w4.w * swa[4*q+3];
            s2 += w4.x * swa[DFEAT+4*q]   + w4.y * swa[DFEAT+4*q+1]
                + w4.z * swa[DFEAT+4*q+2] + w4.w * swa[DFEAT+4*q+3];
        }
        su1[tid] = s1;
        su2[tid] = s2;
        sbc[tid] = b_enc[m * DFEAT + tid] * (swa[tid] + swa[DFEAT + tid]);
    }
    __syncthreads();
    if (tid < 64) {
        float t = sbc[tid] + sbc[tid + 64];
        #pragma unroll
        for (int o = 32; o; o >>= 1) t += __shfl_xor(t, o);
        if (tid == 0) scv = t + b_att[e];
    }
    __syncthreads();

    float4 U1a = ((const float4*)su1)[sub], U1b = ((const float4*)su1)[sub + 16];
    float4 U2a = ((const float4*)su2)[sub], U2b = ((const float4*)su2)[sub + 16];
    float c = scv;

    float mref = 0.f, tmax = -3e38f, sum = 0.f;
    float4 va = make_float4(0.f, 0.f, 0.f, 0.f);
    float4 vb = make_float4(0.f, 0.f, 0.f, 0.f);

#define COMPUTE(R0a, R0b, R3a, R3b)                                          \
    {                                                                        \
        float p = dot4(R0a, U1a) + dot4(R0b, U1b)                            \
                + dot4(R3a, U2a) + dot4(R3b, U2b);                           \
        p += __shfl_xor(p, 1);                                               \
        p += __shfl_xor(p, 2);                                               \
        p += __shfl_xor(p, 4);                                               \
        p += __shfl_xor(p, 8);                                               \
        float s = p + c;                                                     \
        s = s > 0.f ? s : 0.2f * s;                                          \
        tmax = fmaxf(tmax, s);                                               \
        if (tmax > mref + RESCALE_THR) {                                     \
            float r = __expf(mref - tmax);                                   \
            sum *= r;                                                        \
            va.x *= r; va.y *= r; va.z *= r; va.w *= r;                      \
            vb.x *= r; vb.y *= r; vb.z *= r; vb.w *= r;                      \
            mref = tmax;                                                     \
        }                                                                    \
        float pe = __expf(s - mref);                                         \
        sum += pe;                                                           \
        va.x += pe * R3a.x; va.y += pe * R3a.y;                              \
        va.z += pe * R3a.z; va.w += pe * R3a.w;                              \
        vb.x += pe * R3b.x; vb.y += pe * R3b.y;                              \
        vb.z += pe * R3b.z; vb.w += pe * R3b.w;                              \
    }

    // ---- guard-free main loop: rows for i+2G prefetched unconditionally ----
    while (i + 2 * GPP < NINST) {
        const float4* p0 = (const float4*)(feat + (size_t)j2.x * DFEAT);
        const float4* p3 = (const float4*)(feat + (size_t)j2.w * DFEAT);
        float4 C0a = p0[sub], C0b = p0[sub + 16];
        float4 C3a = p3[sub], C3b = p3[sub + 16];
        int nj = i + 3 * GPP;
        nj = nj < NINST ? nj : NINST - 1;   // clamped idx prefetch (16B, harmless)
        int4 j3 = ib4[nj];

        COMPUTE(A0a, A0b, A3a, A3b);

        A0a = B0a; A0b = B0b; A3a = B3a; A3b = B3b;
        B0a = C0a; B0b = C0b; B3a = C3a; B3b = C3b;
        j2 = j3;
        i += GPP;
    }

    // ---- epilogue: 2 remaining instances, rows already in registers ----
    COMPUTE(A0a, A0b, A3a, A3b);
    i += GPP;
    if (i < NINST) COMPUTE(B0a, B0b, B3a, B3b);

#undef COMPUTE

    // ---- block-level flash combine of 16 group states ----
    *(float4*)&sV[gid][sub * 4]      = va;
    *(float4*)&sV[gid][64 + sub * 4] = vb;
    if (sub == 0) { sMx[gid] = mref; sSm[gid] = sum; }
    __syncthreads();

    if (tid < DFEAT) {
        float M = sMx[0];
        #pragma unroll
        for (int k = 1; k < GPB; ++k) M = fmaxf(M, sMx[k]);
        float S = 0.f, V = 0.f;
        #pragma unroll
        for (int k = 0; k < GPB; ++k) {
            float ek = __expf(sMx[k] - M);
            S += ek * sSm[k];
            V += ek * sV[k][tid];
        }
        pV[(size_t)blockIdx.x * DFEAT + tid] = V;
        if (tid == 0) { pM[blockIdx.x] = M; pS[blockIdx.x] = S; }
    }
}

// ---------------------------------------------------------------------------
// Pass 2: per path — flash-combine 128 block partials, normalize, GEMV with
// W_enc, produce mp_out[m][:] and ms[m].  grid = 6 x 256
// ---------------------------------------------------------------------------
__global__ __launch_bounds__(256) void k_pass2(
    const float* __restrict__ pV, const float* __restrict__ pM, const float* __restrict__ pS,
    const float* __restrict__ W_enc, const float* __restrict__ b_enc,
    const float* __restrict__ w_mp, const float* __restrict__ b_mp,
    float* __restrict__ mp_out, float* __restrict__ ms)
{
    int m = blockIdx.x, tid = threadIdx.x;
    int d = tid & 127, slice = tid >> 7;    // 2 slices

    __shared__ float tmp[BPP];
    __shared__ float eL[BPP];
    __shared__ float sv[2][DFEAT];
    __shared__ float sVn[DFEAT];
    __shared__ float smp[DFEAT];
    __shared__ float sS, sMx;

    if (tid < BPP) tmp[tid] = pM[m * BPP + tid];
    __syncthreads();
    for (int off = 64; off; off >>= 1) {
        if (tid < off) tmp[tid] = fmaxf(tmp[tid], tmp[tid + off]);
        __syncthreads();
    }
    if (tid == 0) sMx = tmp[0];
    __syncthreads();
    float M = sMx;

    if (tid < BPP) {
        float ek = __expf(pM[m * BPP + tid] - M);
        eL[tid] = ek;
        tmp[tid] = ek * pS[m * BPP + tid];
    }
    __syncthreads();
    for (int off = 64; off; off >>= 1) {
        if (tid < off) tmp[tid] += tmp[tid + off];
        __syncthreads();
    }
    if (tid == 0) sS = tmp[0];
    __syncthreads();
    float Sinv = 1.f / sS;

    float acc = 0.f;
    for (int k = slice; k < BPP; k += 2)
        acc += eL[k] * pV[((size_t)(m * BPP + k)) * DFEAT + d];
    sv[slice][d] = acc;
    __syncthreads();
    if (tid < DFEAT) sVn[tid] = (sv[0][tid] + sv[1][tid]) * Sinv;
    __syncthreads();

    const float* W = W_enc + (size_t)m * DFEAT * DFEAT;
    float gacc = 0.f;
    for (int dd = slice; dd < DFEAT; dd += 2)
        gacc += sVn[dd] * W[(size_t)dd * DFEAT + d];
    __syncthreads();
    sv[slice][d] = gacc;
    __syncthreads();
    if (tid < DFEAT) {
        float t = sv[0][tid] + sv[1][tid] + b_enc[m * DFEAT + tid];
        mp_out[m * DFEAT + tid] = t;
        smp[tid] = t * w_mp[tid];
    }
    __syncthreads();

    if (tid < 64) {
        float t = smp[tid] + smp[tid + 64];
        #pragma unroll
        for (int o = 32; o; o >>= 1) t += __shfl_xor(t, o);
        if (tid == 0) ms[m] = t + b_mp[0];
    }
}

// ---------------------------------------------------------------------------
// Pass 3: cross-path softmax(leaky_relu(ms)) + blend + ELU.  1 block x 128.
// ---------------------------------------------------------------------------
__global__ void k_final(const float* __restrict__ mp_out, const float* __restrict__ ms,
                        float* __restrict__ out) {
    int h = threadIdx.x;
    float l[NPATH], mx = -3e38f;
    #pragma unroll
    for (int m = 0; m < NPATH; ++m) {
        float x = ms[m];
        x = x > 0.f ? x : 0.2f * x;
        l[m] = x;
        mx = fmaxf(mx, x);
    }
    float sum = 0.f;
    #pragma unroll
    for (int m = 0; m < NPATH; ++m) { l[m] = __expf(l[m] - mx); sum += l[m]; }
    float o = 0.f;
    #pragma unroll
    for (int m = 0; m < NPATH; ++m) o += (l[m] / sum) * mp_out[m * DFEAT + h];
    out[h] = o > 0.f ? o : __expf(o) - 1.f;   // elu
}

// ---------------------------------------------------------------------------
extern "C" void kernel_launch(void* const* d_in, const int* in_sizes, int n_in,
                              void* d_out, int out_size, void* d_ws, size_t ws_size,
                              hipStream_t stream) {
    const float* features   = (const float*)d_in[0];
    const float* W_enc      = (const float*)d_in[1];
    const float* b_enc      = (const float*)d_in[2];
    const float* W_att      = (const float*)d_in[3];
    const float* b_att      = (const float*)d_in[4];
    const float* w_mp       = (const float*)d_in[5];
    const float* b_mp       = (const float*)d_in[6];
    const int*   instances  = (const int*)d_in[7];
    const int*   edge_types = (const int*)d_in[8];
    float* out = (float*)d_out;
    float* ws  = (float*)d_ws;

    const int nblk1 = NPATH * BPP;                    // 768

    float* pV     = ws;                               // 768*128
    float* pM     = pV + (size_t)nblk1 * DFEAT;       // 768
    float* pS     = pM + nblk1;                       // 768
    float* mp_out = pS + nblk1;                       // 768
    float* msv    = mp_out + NPATH * DFEAT;           // 6

    k_pass1<<<nblk1, TPB1, 0, stream>>>(features, instances, W_enc, b_enc,
                                        W_att, b_att, edge_types, pV, pM, pS);

    k_pass2<<<NPATH, 256, 0, stream>>>(pV, pM, pS, W_enc, b_enc, w_mp, b_mp, mp_out, msv);

    k_final<<<1, DFEAT, 0, stream>>>(mp_out, msv, out);
}